// Round 3
// baseline (1476.640 us; speedup 1.0000x reference)
//
#include <hip/hip_runtime.h>

#define HD 64
#define TT 512
#define BB 256
#define NROWS (BB * TT)  // 131072

typedef __attribute__((ext_vector_type(2))) float f32x2;

// ---------- helpers ----------
__device__ __forceinline__ float rl(float v, int k) {
  return __uint_as_float(__builtin_amdgcn_readlane(__float_as_uint(v), k));
}
__device__ __forceinline__ float wsum(float v) {
#pragma unroll
  for (int m = 32; m >= 1; m >>= 1) v += __shfl_xor(v, m, 64);
  return v;
}
__device__ __forceinline__ float sigmoidf_(float x) {
  return 1.0f / (1.0f + __expf(-x));
}
__device__ __forceinline__ float tanhf_(float x) {
  return 1.0f - 2.0f / (__expf(2.0f * x) + 1.0f);
}
__device__ __forceinline__ unsigned short f2bf(float f) {
  unsigned int u = __float_as_uint(f);
  u = (u + 0x7fffu + ((u >> 16) & 1u)) >> 16;
  return (unsigned short)u;
}
__device__ __forceinline__ float ldz(const float* p) { return *p; }
__device__ __forceinline__ float ldz(const unsigned short* p) {
  return __uint_as_float(((unsigned int)(*p)) << 16);
}
__device__ __forceinline__ void store8(float* p, float4 a, float4 b) {
  *(float4*)p = a;
  *(float4*)(p + 4) = b;
}
__device__ __forceinline__ void store8(unsigned short* p, float4 a, float4 b) {
  union { unsigned short us[8]; int4 v; } u;
  u.us[0] = f2bf(a.x); u.us[1] = f2bf(a.y); u.us[2] = f2bf(a.z); u.us[3] = f2bf(a.w);
  u.us[4] = f2bf(b.x); u.us[5] = f2bf(b.y); u.us[6] = f2bf(b.z); u.us[7] = f2bf(b.w);
  *(int4*)p = u.v;
}
__device__ __forceinline__ float4 fma4(float4 a, float s, float4 w) {
  a.x += s * w.x; a.y += s * w.y; a.z += s * w.z; a.w += s * w.w;
  return a;
}
__device__ __forceinline__ float4 add4(float4 a, float4 b) {
  a.x += b.x; a.y += b.y; a.z += b.z; a.w += b.w;
  return a;
}
__device__ __forceinline__ f32x2 pf2(f32x2 a, float s, f32x2 w) {
  a.x += s * w.x;
  a.y += s * w.y;
  return a;
}

// ---------- Kernel A: xy = [LN(action@W_act+b_act), relu(...)]; Zx = xy @ W_lstm[0:128] + b_lstm ----------
template <typename ZT>
__global__ __launch_bounds__(256) void kA(const float* __restrict__ act,
                                          const float* __restrict__ Wact,
                                          const float* __restrict__ bact,
                                          const float* __restrict__ g2,
                                          const float* __restrict__ beta2,
                                          const float* __restrict__ Wl,
                                          const float* __restrict__ bl,
                                          ZT* __restrict__ Zx) {
  __shared__ float xy[64][128];
  const int tid = threadIdx.x;
  const int lane = tid & 63;
  const int wv = tid >> 6;
  const int r0blk = blockIdx.x * 64;

  float wreg[64];
#pragma unroll
  for (int k = 0; k < 64; ++k) wreg[k] = Wact[k * 64 + lane];
  const float ba = bact[lane], gg = g2[lane], bb = beta2[lane];

  for (int i = 0; i < 16; ++i) {
    const int r = i * 4 + wv;
    const int row = r0blk + r;
    const float a = act[row * 64 + lane];
    float yd = ba;
#pragma unroll
    for (int k = 0; k < 64; ++k) yd += rl(a, k) * wreg[k];
    const float mu = wsum(yd) * (1.0f / 64.0f);
    const float d = yd - mu;
    const float var = wsum(d * d) * (1.0f / 64.0f);
    const float x = d * rsqrtf(var + 1e-12f) * gg + bb;
    xy[r][lane] = x;
    xy[r][64 + lane] = fmaxf(yd, 0.0f);
  }
  __syncthreads();

  const int tc = tid & 31;
  const int tr = tid >> 5;
  const int c0 = tc * 8;
  float4 accA[8], accB[8];
#pragma unroll
  for (int r = 0; r < 8; ++r) {
    accA[r] = make_float4(0.f, 0.f, 0.f, 0.f);
    accB[r] = make_float4(0.f, 0.f, 0.f, 0.f);
  }
  for (int kk = 0; kk < 128; kk += 4) {
    float4 xv[8];
#pragma unroll
    for (int r = 0; r < 8; ++r) xv[r] = *(const float4*)&xy[tr * 8 + r][kk];
#pragma unroll
    for (int dk = 0; dk < 4; ++dk) {
      const float4 wa = *(const float4*)&Wl[(kk + dk) * 256 + c0];
      const float4 wb = *(const float4*)&Wl[(kk + dk) * 256 + c0 + 4];
#pragma unroll
      for (int r = 0; r < 8; ++r) {
        const float xr = (dk == 0) ? xv[r].x : (dk == 1) ? xv[r].y : (dk == 2) ? xv[r].z : xv[r].w;
        accA[r] = fma4(accA[r], xr, wa);
        accB[r] = fma4(accB[r], xr, wb);
      }
    }
  }
  const float4 bla = *(const float4*)&bl[c0];
  const float4 blb = *(const float4*)&bl[c0 + 4];
#pragma unroll
  for (int r = 0; r < 8; ++r) {
    const int row = r0blk + tr * 8 + r;
    store8(&Zx[(size_t)row * 256 + c0], add4(accA[r], bla), add4(accB[r], blb));
  }
}

// ---------- Kernel B v3: LSTM scan, one wave per batch, 4 cols/lane, no LDS, no barriers ----------
template <typename ZT>
__global__ __launch_bounds__(64, 1) void kB3(const ZT* __restrict__ Zx,
                                             const float* __restrict__ Wl,
                                             const float* __restrict__ c0p,
                                             const float* __restrict__ h0p,
                                             float* __restrict__ hs,
                                             float* __restrict__ cfin,
                                             float* __restrict__ hfin) {
  const int l = threadIdx.x;
  const int b = blockIdx.x;

  // Lane l owns output columns l (i), 64+l (j), 128+l (f), 192+l (o).
  // Weights: 64 k x 4 cols = 256 f32 VGPRs, packed as f32x2 pairs for v_pk_fma_f32.
  f32x2 wij[64], wfo[64];
#pragma unroll
  for (int k = 0; k < 64; ++k) {
    const float* wr = &Wl[(128 + k) * 256];
    f32x2 a, bvec;
    a.x = wr[l];       a.y = wr[64 + l];
    bvec.x = wr[128 + l]; bvec.y = wr[192 + l];
    wij[k] = a;
    wfo[k] = bvec;
  }

  float c = c0p[b * 64 + l];
  float h = h0p[b * 64 + l];

  const ZT* zrow = Zx + (size_t)b * TT * 256;
  float* hsrow = hs + (size_t)b * TT * 64;

#define LD4(PI, PJ, PF, PO, T)                       \
  PI = ldz(&zrow[(size_t)(T) * 256 + 0 + l]);        \
  PJ = ldz(&zrow[(size_t)(T) * 256 + 64 + l]);       \
  PF = ldz(&zrow[(size_t)(T) * 256 + 128 + l]);      \
  PO = ldz(&zrow[(size_t)(T) * 256 + 192 + l]);

  float pAi, pAj, pAf, pAo, pBi, pBj, pBf, pBo;
  float pCi, pCj, pCf, pCo, pDi, pDj, pDf, pDo;
  LD4(pAi, pAj, pAf, pAo, 0)
  LD4(pBi, pBj, pBf, pBo, 1)
  LD4(pCi, pCj, pCf, pCo, 2)
  LD4(pDi, pDj, pDf, pDo, 3)

#define STEP(PI, PJ, PF, PO, T)                                               \
  {                                                                           \
    f32x2 a0, a1, a2, a3, f0, f1, f2, f3;                                     \
    a0.x = PI; a0.y = PJ; f0.x = PF; f0.y = PO;                               \
    a1 = a2 = a3 = f1 = f2 = f3 = (f32x2)(0.0f);                              \
    _Pragma("unroll") for (int k = 0; k < 64; k += 4) {                       \
      const float h0v = rl(h, k), h1v = rl(h, k + 1);                         \
      const float h2v = rl(h, k + 2), h3v = rl(h, k + 3);                     \
      a0 = pf2(a0, h0v, wij[k]);     f0 = pf2(f0, h0v, wfo[k]);               \
      a1 = pf2(a1, h1v, wij[k + 1]); f1 = pf2(f1, h1v, wfo[k + 1]);           \
      a2 = pf2(a2, h2v, wij[k + 2]); f2 = pf2(f2, h2v, wfo[k + 2]);           \
      a3 = pf2(a3, h3v, wij[k + 3]); f3 = pf2(f3, h3v, wfo[k + 3]);           \
    }                                                                         \
    a0.x += a1.x; a0.y += a1.y; a2.x += a3.x; a2.y += a3.y;                   \
    f0.x += f1.x; f0.y += f1.y; f2.x += f3.x; f2.y += f3.y;                   \
    const float zi = a0.x + a2.x, zj = a0.y + a2.y;                           \
    const float zf = f0.x + f2.x, zo = f0.y + f2.y;                           \
    int tn = (T) + 4;                                                         \
    if (tn > TT - 1) tn = TT - 1;                                             \
    LD4(PI, PJ, PF, PO, tn)                                                   \
    c = c * sigmoidf_(zf + 1.0f) + sigmoidf_(zi) * tanhf_(zj);                \
    h = sigmoidf_(zo) * tanhf_(c);                                            \
    hsrow[(size_t)(T) * 64 + l] = h;                                          \
  }

#pragma unroll 1
  for (int t = 0; t < TT; t += 4) {
    STEP(pAi, pAj, pAf, pAo, t)
    STEP(pBi, pBj, pBf, pBo, t + 1)
    STEP(pCi, pCj, pCf, pCo, t + 2)
    STEP(pDi, pDj, pDf, pDo, t + 3)
  }
#undef STEP
#undef LD4

  cfin[b * 64 + l] = c;
  hfin[b * 64 + l] = h;
}

// ---------- Kernel C: out = LN(hs) ; q = out @ W_out + b_out ----------
__global__ __launch_bounds__(256) void kC(const float* __restrict__ hs,
                                          const float* __restrict__ g3,
                                          const float* __restrict__ beta3,
                                          const float* __restrict__ Wout,
                                          const float* __restrict__ bout,
                                          float* __restrict__ q) {
  const int lane = threadIdx.x & 63;
  const int wv = threadIdx.x >> 6;
  const float g = g3[lane], be = beta3[lane], wo = Wout[lane], bo = bout[0];
  for (int n = blockIdx.x * 4 + wv; n < NROWS; n += gridDim.x * 4) {
    const float v = hs[(size_t)n * 64 + lane];
    const float mu = wsum(v) * (1.0f / 64.0f);
    const float d = v - mu;
    const float var = wsum(d * d) * (1.0f / 64.0f);
    const float xn = d * rsqrtf(var + 1e-12f) * g + be;
    const float s = wsum(xn * wo);
    if (lane == 0) q[n] = s + bo;
  }
}

// ---------- launch ----------
extern "C" void kernel_launch(void* const* d_in, const int* in_sizes, int n_in,
                              void* d_out, int out_size, void* d_ws, size_t ws_size,
                              hipStream_t stream) {
  const float* action = (const float*)d_in[1];
  const float* c0 = (const float*)d_in[2];
  const float* h0 = (const float*)d_in[3];
  const float* Wact = (const float*)d_in[8];
  const float* bact = (const float*)d_in[9];
  const float* g2 = (const float*)d_in[10];
  const float* b2 = (const float*)d_in[11];
  const float* Wl = (const float*)d_in[12];
  const float* bl = (const float*)d_in[13];
  const float* g3 = (const float*)d_in[14];
  const float* b3 = (const float*)d_in[15];
  const float* Wout = (const float*)d_in[16];
  const float* bout = (const float*)d_in[17];

  float* q = (float*)d_out;
  float* cfin = q + NROWS;
  float* hfin = cfin + BB * HD;

  const size_t zx32 = (size_t)NROWS * 256 * sizeof(float);
  const size_t zx16 = (size_t)NROWS * 256 * sizeof(unsigned short);
  const size_t hsb = (size_t)NROWS * 64 * sizeof(float);

  if (ws_size >= zx32 + hsb) {
    float* Zx = (float*)d_ws;
    float* hs = (float*)((char*)d_ws + zx32);
    kA<float><<<NROWS / 64, 256, 0, stream>>>(action, Wact, bact, g2, b2, Wl, bl, Zx);
    kB3<float><<<BB, 64, 0, stream>>>(Zx, Wl, c0, h0, hs, cfin, hfin);
    kC<<<2048, 256, 0, stream>>>(hs, g3, b3, Wout, bout, q);
  } else {
    unsigned short* Zx = (unsigned short*)d_ws;
    float* hs = (float*)((char*)d_ws + zx16);
    kA<unsigned short><<<NROWS / 64, 256, 0, stream>>>(action, Wact, bact, g2, b2, Wl, bl, Zx);
    kB3<unsigned short><<<BB, 64, 0, stream>>>(Zx, Wl, c0, h0, hs, cfin, hfin);
    kC<<<2048, 256, 0, stream>>>(hs, g3, b3, Wout, bout, q);
  }
}

// Round 5
// 484.141 us; speedup vs baseline: 3.0500x; 3.0500x over previous
//
#include <hip/hip_runtime.h>

#define HD 64
#define TT 512
#define BB 256
#define NROWS (BB * TT)  // 131072

typedef _Float16 half2_t __attribute__((ext_vector_type(2)));

// ---------- helpers ----------
__device__ __forceinline__ float rl(float v, int k) {
  return __uint_as_float(__builtin_amdgcn_readlane(__float_as_uint(v), k));
}
__device__ __forceinline__ float wsum(float v) {
#pragma unroll
  for (int m = 32; m >= 1; m >>= 1) v += __shfl_xor(v, m, 64);
  return v;
}
__device__ __forceinline__ float sigmoidf_(float x) {
  return 1.0f / (1.0f + __expf(-x));
}
__device__ __forceinline__ float tanhf_(float x) {
  return 1.0f - 2.0f / (__expf(2.0f * x) + 1.0f);
}
__device__ __forceinline__ unsigned short f2bf(float f) {
  unsigned int u = __float_as_uint(f);
  u = (u + 0x7fffu + ((u >> 16) & 1u)) >> 16;
  return (unsigned short)u;
}
__device__ __forceinline__ float ldz(const float* p) { return *p; }
__device__ __forceinline__ float ldz(const unsigned short* p) {
  return __uint_as_float(((unsigned int)(*p)) << 16);
}
__device__ __forceinline__ void store8(float* p, float4 a, float4 b) {
  *(float4*)p = a;
  *(float4*)(p + 4) = b;
}
__device__ __forceinline__ void store8(unsigned short* p, float4 a, float4 b) {
  union { unsigned short us[8]; int4 v; } u;
  u.us[0] = f2bf(a.x); u.us[1] = f2bf(a.y); u.us[2] = f2bf(a.z); u.us[3] = f2bf(a.w);
  u.us[4] = f2bf(b.x); u.us[5] = f2bf(b.y); u.us[6] = f2bf(b.z); u.us[7] = f2bf(b.w);
  *(int4*)p = u.v;
}
__device__ __forceinline__ float4 fma4(float4 a, float s, float4 w) {
  a.x += s * w.x; a.y += s * w.y; a.z += s * w.z; a.w += s * w.w;
  return a;
}
__device__ __forceinline__ float4 add4(float4 a, float4 b) {
  a.x += b.x; a.y += b.y; a.z += b.z; a.w += b.w;
  return a;
}

// dot2: acc += a.x*b.x + a.y*b.y  (f16 inputs, f32 accumulate)
__device__ __forceinline__ float dot2(half2_t a, half2_t b, float acc) {
#if __has_builtin(__builtin_amdgcn_fdot2)
  return __builtin_amdgcn_fdot2(a, b, acc, false);
#else
  return acc + (float)a.x * (float)b.x + (float)a.y * (float)b.y;
#endif
}

// pack two f32 into half2_t via v_cvt_pkrtz_f16_f32 (bit_cast fixes builtin's __fp16 vec type)
__device__ __forceinline__ half2_t pkrtz(float a, float b) {
  return __builtin_bit_cast(half2_t, __builtin_amdgcn_cvt_pkrtz(a, b));
}

// ---------- Kernel A: xy = [LN(action@W_act+b_act), relu(...)]; Zx = xy @ W_lstm[0:128] + b_lstm ----------
template <typename ZT>
__global__ __launch_bounds__(256) void kA(const float* __restrict__ act,
                                          const float* __restrict__ Wact,
                                          const float* __restrict__ bact,
                                          const float* __restrict__ g2,
                                          const float* __restrict__ beta2,
                                          const float* __restrict__ Wl,
                                          const float* __restrict__ bl,
                                          ZT* __restrict__ Zx) {
  __shared__ float xy[64][128];
  const int tid = threadIdx.x;
  const int lane = tid & 63;
  const int wv = tid >> 6;
  const int r0blk = blockIdx.x * 64;

  float wreg[64];
#pragma unroll
  for (int k = 0; k < 64; ++k) wreg[k] = Wact[k * 64 + lane];
  const float ba = bact[lane], gg = g2[lane], bb = beta2[lane];

  for (int i = 0; i < 16; ++i) {
    const int r = i * 4 + wv;
    const int row = r0blk + r;
    const float a = act[row * 64 + lane];
    float yd = ba;
#pragma unroll
    for (int k = 0; k < 64; ++k) yd += rl(a, k) * wreg[k];
    const float mu = wsum(yd) * (1.0f / 64.0f);
    const float d = yd - mu;
    const float var = wsum(d * d) * (1.0f / 64.0f);
    const float x = d * rsqrtf(var + 1e-12f) * gg + bb;
    xy[r][lane] = x;
    xy[r][64 + lane] = fmaxf(yd, 0.0f);
  }
  __syncthreads();

  const int tc = tid & 31;
  const int tr = tid >> 5;
  const int c0 = tc * 8;
  float4 accA[8], accB[8];
#pragma unroll
  for (int r = 0; r < 8; ++r) {
    accA[r] = make_float4(0.f, 0.f, 0.f, 0.f);
    accB[r] = make_float4(0.f, 0.f, 0.f, 0.f);
  }
  for (int kk = 0; kk < 128; kk += 4) {
    float4 xv[8];
#pragma unroll
    for (int r = 0; r < 8; ++r) xv[r] = *(const float4*)&xy[tr * 8 + r][kk];
#pragma unroll
    for (int dk = 0; dk < 4; ++dk) {
      const float4 wa = *(const float4*)&Wl[(kk + dk) * 256 + c0];
      const float4 wb = *(const float4*)&Wl[(kk + dk) * 256 + c0 + 4];
#pragma unroll
      for (int r = 0; r < 8; ++r) {
        const float xr = (dk == 0) ? xv[r].x : (dk == 1) ? xv[r].y : (dk == 2) ? xv[r].z : xv[r].w;
        accA[r] = fma4(accA[r], xr, wa);
        accB[r] = fma4(accB[r], xr, wb);
      }
    }
  }
  const float4 bla = *(const float4*)&bl[c0];
  const float4 blb = *(const float4*)&bl[c0 + 4];
#pragma unroll
  for (int r = 0; r < 8; ++r) {
    const int row = r0blk + tr * 8 + r;
    store8(&Zx[(size_t)row * 256 + c0], add4(accA[r], bla), add4(accB[r], blb));
  }
}

// ---------- Kernel B v4: wave per batch, lane-local gates, packed-f16 weights + dot2 ----------
template <typename ZT>
__global__ __launch_bounds__(64, 1) void kB4(const ZT* __restrict__ Zx,
                                             const float* __restrict__ Wl,
                                             const float* __restrict__ c0p,
                                             const float* __restrict__ h0p,
                                             float* __restrict__ hs,
                                             float* __restrict__ cfin,
                                             float* __restrict__ hfin) {
  const int l = threadIdx.x;
  const int b = blockIdx.x;

  // Lane l owns z columns l (i), 64+l (j), 128+l (f), 192+l (o).
  // Weight pair p = (k=p, k=p+32), packed f16: 4 gates x 32 pairs = 128 VGPRs.
  half2_t wi[32], wj[32], wf[32], wo[32];
#pragma unroll
  for (int p = 0; p < 32; ++p) {
    const float* r0 = &Wl[(128 + p) * 256];
    const float* r1 = &Wl[(128 + p + 32) * 256];
    wi[p] = pkrtz(r0[l], r1[l]);
    wj[p] = pkrtz(r0[64 + l], r1[64 + l]);
    wf[p] = pkrtz(r0[128 + l], r1[128 + l]);
    wo[p] = pkrtz(r0[192 + l], r1[192 + l]);
  }

  float c = c0p[b * 64 + l];
  float h = h0p[b * 64 + l];

  const ZT* zrow = Zx + (size_t)b * TT * 256;
  float* hsrow = hs + (size_t)b * TT * 64;

#define LD4(PI, PJ, PF, PO, T)                       \
  PI = ldz(&zrow[(size_t)(T) * 256 + 0 + l]);        \
  PJ = ldz(&zrow[(size_t)(T) * 256 + 64 + l]);       \
  PF = ldz(&zrow[(size_t)(T) * 256 + 128 + l]);      \
  PO = ldz(&zrow[(size_t)(T) * 256 + 192 + l]);

  float pAi, pAj, pAf, pAo, pBi, pBj, pBf, pBo;
  float pCi, pCj, pCf, pCo, pDi, pDj, pDf, pDo;
  LD4(pAi, pAj, pAf, pAo, 0)
  LD4(pBi, pBj, pBf, pBo, 1)
  LD4(pCi, pCj, pCf, pCo, 2)
  LD4(pDi, pDj, pDf, pDo, 3)

#define STEP(PI, PJ, PF, PO, T)                                               \
  {                                                                           \
    const float hx = __shfl_xor(h, 32, 64);                                   \
    const half2_t hp = pkrtz(h, hx);                                          \
    const unsigned int hpu = __builtin_bit_cast(unsigned int, hp);            \
    float zi = PI, zj = PJ, zf = PF, zo = PO;                                 \
    _Pragma("unroll") for (int p = 0; p < 32; ++p) {                          \
      const unsigned int hu = __builtin_amdgcn_readlane(hpu, p);              \
      const half2_t hb = __builtin_bit_cast(half2_t, hu);                     \
      zi = dot2(hb, wi[p], zi);                                               \
      zj = dot2(hb, wj[p], zj);                                               \
      zf = dot2(hb, wf[p], zf);                                               \
      zo = dot2(hb, wo[p], zo);                                               \
    }                                                                         \
    int tn = (T) + 4;                                                         \
    if (tn > TT - 1) tn = TT - 1;                                             \
    LD4(PI, PJ, PF, PO, tn)                                                   \
    c = c * sigmoidf_(zf + 1.0f) + sigmoidf_(zi) * tanhf_(zj);                \
    h = sigmoidf_(zo) * tanhf_(c);                                            \
    hsrow[(size_t)(T) * 64 + l] = h;                                          \
  }

#pragma unroll 1
  for (int t = 0; t < TT; t += 4) {
    STEP(pAi, pAj, pAf, pAo, t)
    STEP(pBi, pBj, pBf, pBo, t + 1)
    STEP(pCi, pCj, pCf, pCo, t + 2)
    STEP(pDi, pDj, pDf, pDo, t + 3)
  }
#undef STEP
#undef LD4

  cfin[b * 64 + l] = c;
  hfin[b * 64 + l] = h;
}

// ---------- Kernel C: out = LN(hs) ; q = out @ W_out + b_out ----------
__global__ __launch_bounds__(256) void kC(const float* __restrict__ hs,
                                          const float* __restrict__ g3,
                                          const float* __restrict__ beta3,
                                          const float* __restrict__ Wout,
                                          const float* __restrict__ bout,
                                          float* __restrict__ q) {
  const int lane = threadIdx.x & 63;
  const int wv = threadIdx.x >> 6;
  const float g = g3[lane], be = beta3[lane], wo = Wout[lane], bo = bout[0];
  for (int n = blockIdx.x * 4 + wv; n < NROWS; n += gridDim.x * 4) {
    const float v = hs[(size_t)n * 64 + lane];
    const float mu = wsum(v) * (1.0f / 64.0f);
    const float d = v - mu;
    const float var = wsum(d * d) * (1.0f / 64.0f);
    const float xn = d * rsqrtf(var + 1e-12f) * g + be;
    const float s = wsum(xn * wo);
    if (lane == 0) q[n] = s + bo;
  }
}

// ---------- launch ----------
extern "C" void kernel_launch(void* const* d_in, const int* in_sizes, int n_in,
                              void* d_out, int out_size, void* d_ws, size_t ws_size,
                              hipStream_t stream) {
  const float* action = (const float*)d_in[1];
  const float* c0 = (const float*)d_in[2];
  const float* h0 = (const float*)d_in[3];
  const float* Wact = (const float*)d_in[8];
  const float* bact = (const float*)d_in[9];
  const float* g2 = (const float*)d_in[10];
  const float* b2 = (const float*)d_in[11];
  const float* Wl = (const float*)d_in[12];
  const float* bl = (const float*)d_in[13];
  const float* g3 = (const float*)d_in[14];
  const float* b3 = (const float*)d_in[15];
  const float* Wout = (const float*)d_in[16];
  const float* bout = (const float*)d_in[17];

  float* q = (float*)d_out;
  float* cfin = q + NROWS;
  float* hfin = cfin + BB * HD;

  const size_t zx32 = (size_t)NROWS * 256 * sizeof(float);
  const size_t zx16 = (size_t)NROWS * 256 * sizeof(unsigned short);
  const size_t hsb = (size_t)NROWS * 64 * sizeof(float);

  if (ws_size >= zx32 + hsb) {
    float* Zx = (float*)d_ws;
    float* hs = (float*)((char*)d_ws + zx32);
    kA<float><<<NROWS / 64, 256, 0, stream>>>(action, Wact, bact, g2, b2, Wl, bl, Zx);
    kB4<float><<<BB, 64, 0, stream>>>(Zx, Wl, c0, h0, hs, cfin, hfin);
    kC<<<2048, 256, 0, stream>>>(hs, g3, b3, Wout, bout, q);
  } else {
    unsigned short* Zx = (unsigned short*)d_ws;
    float* hs = (float*)((char*)d_ws + zx16);
    kA<unsigned short><<<NROWS / 64, 256, 0, stream>>>(action, Wact, bact, g2, b2, Wl, bl, Zx);
    kB4<unsigned short><<<BB, 64, 0, stream>>>(Zx, Wl, c0, h0, hs, cfin, hfin);
    kC<<<2048, 256, 0, stream>>>(hs, g3, b3, Wout, bout, q);
  }
}